// Round 4
// baseline (314.729 us; speedup 1.0000x reference)
//
#include <hip/hip_runtime.h>
#include <hip/hip_bf16.h>

typedef __bf16 bf16_t;
typedef __attribute__((ext_vector_type(8))) __bf16 bf16x8;
typedef __attribute__((ext_vector_type(4))) float f32x4;

#define C_IN   256
#define C_OUT  512
#define HW     3136      // 56*56
#define NB     32        // batch
#define HP     58        // 56 + 2 halo
#define NQBLK  36864     // (512*256*9)/32 quant blocks

// conv-GEMM geometry: BM=256 (co), BN=224 (4 image rows x 56), K = 9 pos x 4 ci-chunks of 64
#define BM   256
#define BN   224
#define BPIX 352         // 6 x 58 = 348 halo pixels, padded to 352 rows
#define NWG  896         // 448 s-bands (32 img x 14) x 2 co-blocks

// ---- async global->LDS, 16B per lane (dest = wave-uniform base + lane*16) ----
typedef const __attribute__((address_space(1))) unsigned int gu32;
typedef __attribute__((address_space(3))) unsigned int lu32;
__device__ __forceinline__ void gl16(const void* g, void* l) {
    __builtin_amdgcn_global_load_lds((gu32*)g, (lu32*)l, 16, 0, 0);
}
#define BAR()    __builtin_amdgcn_s_barrier()
#define PRIO(x)  __builtin_amdgcn_s_setprio(x)
#define SCHED0() __builtin_amdgcn_sched_barrier(0)

// ---------------- kernel 1: 6-bit fake-quant + repack to Wt[p][co][ci] (bf16) ----------------
__global__ void k_dequant(const float* __restrict__ w, bf16_t* __restrict__ wt) {
    int b = blockIdx.x * blockDim.x + threadIdx.x;
    if (b >= NQBLK) return;
    const float* src = w + (size_t)b * 32;
    float v[32];
    float amax = 0.f;
    #pragma unroll
    for (int i = 0; i < 32; i += 4) {
        float4 t = *reinterpret_cast<const float4*>(src + i);
        v[i] = t.x; v[i+1] = t.y; v[i+2] = t.z; v[i+3] = t.w;
        amax = fmaxf(amax, fmaxf(fmaxf(fabsf(t.x), fabsf(t.y)),
                                 fmaxf(fabsf(t.z), fabsf(t.w))));
    }
    float scale = amax / 31.0f;
    if (scale == 0.f) scale = 1.f;
    #pragma unroll
    for (int i = 0; i < 32; i++) {
        float q = rintf(v[i] / scale);            // jnp.round = RNE = rintf
        q = fminf(31.f, fmaxf(-32.f, q));
        float dq = q * scale;
        int flat = b * 32 + i;                    // flat over OIHW
        int p    = flat % 9;
        int rest = flat / 9;
        int ci   = rest & 255;
        int co   = rest >> 8;
        wt[((size_t)(p * C_OUT + co) << 8) + ci] = (bf16_t)dq;
    }
}

// ---------------- kernel 1b: zero the 1-pixel halo ring of xT ----------------
__global__ void k_halo_zero(bf16_t* __restrict__ xT) {
    int idx = blockIdx.x * 256 + threadIdx.x;
    if (idx >= NB * 228 * 32) return;
    int c8 = idx & 31;
    int t  = idx >> 5;
    int p  = t % 228;
    int n  = t / 228;
    int hh, ww;
    if      (p < 58)  { hh = 0;           ww = p; }
    else if (p < 116) { hh = 57;          ww = p - 58; }
    else if (p < 172) { hh = p - 116 + 1; ww = 0; }
    else              { hh = p - 172 + 1; ww = 57; }
    size_t e = (((size_t)n * HP + hh) * HP + ww) * C_IN + c8 * 8;
    *reinterpret_cast<uint4*>(xT + e) = make_uint4(0, 0, 0, 0);
}

// ------- kernel 2: x NCHW fp32 -> halo-padded NHWC bf16 (xT[n][58][58][ci]) -------
__global__ void k_x_nhwc(const float* __restrict__ x, bf16_t* __restrict__ xT) {
    __shared__ float tile[64][65];
    const int n   = blockIdx.z;
    const int cb  = blockIdx.y * 64;
    const int hwb = blockIdx.x * 64;
    const int t   = threadIdx.x;

    const int col = t & 63;
    const int r0  = t >> 6;
    #pragma unroll
    for (int k = 0; k < 16; k++) {
        int r = r0 * 16 + k;
        tile[r][col] = x[((size_t)(n * C_IN + cb + r)) * HW + hwb + col];
    }
    __syncthreads();

    const int j  = t >> 2;
    const int co = (t & 3) * 16;
    const int hw = hwb + j;
    const int hh = hw / 56, ww = hw - hh * 56;
    __align__(16) bf16_t vals[16];
    #pragma unroll
    for (int k = 0; k < 16; k++)
        vals[k] = (bf16_t)tile[co + k][j];
    bf16_t* dst = xT + (((size_t)n * HP + hh + 1) * HP + (ww + 1)) * C_IN + cb + co;
    *reinterpret_cast<uint4*>(dst)     = *reinterpret_cast<uint4*>(&vals[0]);
    *reinterpret_cast<uint4*>(dst + 8) = *reinterpret_cast<uint4*>(&vals[8]);
}

// ---------------- kernel 3: implicit-GEMM conv with LDS halo band ----------------
// 8 waves as 4(M) x 2(N): wave tile = 64(co) x 112(pixels); acc[4][7] f32x4.
// A (weights): dbuf [2][256][64], staged per tile (4 gl16/thread).
// B (pixels):  per-ci-chunk halo band [2][352][64] = 6 padded rows x 58, staged once per
//              9 position-tiles; position p reads at LDS row offset sh = dh*58+dw.
// XOR swizzle chunk^=(row&7) on both (pre-swizzled global source, swizzled ds_read).
// One barrier + one vmcnt(0) per tile: reads of tile t complete (implicit lgkmcnt before
// MFMA) before BAR(t+1), which releases writes into buf (t+2)&1 == t&1. No phase lockstep.
__global__ __launch_bounds__(512, 2) void k_conv_gemm(
    const bf16_t* __restrict__ xT, const bf16_t* __restrict__ wt,
    const float* __restrict__ bias, float* __restrict__ out)
{
    __shared__ __align__(16) bf16_t As[2][BM][64];     // 64 KB
    __shared__ __align__(16) bf16_t Bs[2][BPIX][64];   // 88 KB  (total 152 KB)

    const int tid  = threadIdx.x;
    const int lane = tid & 63;
    const int wid  = tid >> 6;
    const int wr   = wid >> 1;      // 0..3 -> co slice of 64
    const int wc   = wid & 1;       // 0..1 -> pixel slice of 112

    // bijective XCD swizzle: 896 = 8 x 112; co-fastest within chunk
    const int orig  = blockIdx.x;
    const int wgid  = (orig & 7) * 112 + (orig >> 3);
    const int co0   = (wgid & 1) * BM;
    const int sband = wgid >> 1;              // 0..447
    const int nimg  = sband / 14;
    const int R0    = (sband - nimg * 14) * 4;   // first output row of band

    // ---- staging geometry: thread covers row (tid>>3) per 64-row issue, chunk (tid&7)
    const int prow = tid >> 3;                 // 0..63
    const int lcx  = (tid & 7) ^ (prow & 7);   // pre-swizzled source chunk

    const bf16_t* pAsrc = wt + ((size_t)(co0 + prow) << 8) + lcx * 8;
    const bf16_t* pBsrc = xT + ((size_t)(nimg * HP + R0) * HP + prow) * C_IN + lcx * 8;

    auto stageA = [&](int buf, int c, int p) {
        const bf16_t* src = pAsrc + ((size_t)p << 17) + (c << 6);
        bf16_t* dst = &As[buf][wid * 8][0];
        #pragma unroll
        for (int i = 0; i < 4; i++)
            gl16(src + (i << 14), dst + i * 4096);          // 64 rows x 64 elems per issue
    };
    auto stageB = [&](int buf, int c) {
        const bf16_t* src = pBsrc + (c << 6);
        bf16_t* dst = &Bs[buf][wid * 8][0];
        #pragma unroll
        for (int i = 0; i < 5; i++)
            gl16(src + i * 16384, dst + i * 4096);          // 64 pixels per issue
        if (tid < 224)                                       // tail: pixels 320..347
            gl16(src + 5 * 16384, dst + 5 * 4096);
    };

    // ---- fragment constants ----
    const int rl = lane & 15;
    const int kg = lane >> 4;                  // k-group 0..3

    int a_off[4][2];
    #pragma unroll
    for (int m = 0; m < 4; m++) {
        int row = wr * 64 + m * 16 + rl;
        a_off[m][0] = row * 64 + ((kg       ^ (rl & 7)) * 8);
        a_off[m][1] = row * 64 + (((4 + kg) ^ (rl & 7)) * 8);
    }
    int base_pix[7];
    #pragma unroll
    for (int j = 0; j < 7; j++) {
        int nn = wc * 112 + j * 16 + rl;
        int br = nn / 56, bc = nn - br * 56;
        base_pix[j] = (br + 1) * 58 + bc + 1;
    }

    f32x4 acc[4][7];
    #pragma unroll
    for (int m = 0; m < 4; m++)
        #pragma unroll
        for (int j = 0; j < 7; j++)
            acc[m][j] = f32x4{0.f, 0.f, 0.f, 0.f};

    // ---- prologue: B(chunk0) + A(tile0); full drain; barrier ----
    stageB(0, 0);
    stageA(0, 0, 0);
    asm volatile("s_waitcnt vmcnt(0)" ::: "memory");
    BAR();
    SCHED0();

    bf16x8 aF[4][2], bF[7][2];

    #pragma unroll 1
    for (int c = 0; c < 4; ++c) {
        const int cb = c & 1;
        #pragma unroll 1
        for (int p = 0; p < 9; ++p) {
            const int t    = c * 9 + p;
            const int tpar = t & 1;

            // ---- issue next-tile stages (into buffers nobody reads this tile) ----
            if (t + 1 < 36) {
                int pn = (p == 8) ? 0 : p + 1;
                int cn = (p == 8) ? c + 1 : c;
                stageA(tpar ^ 1, cn, pn);
            }
            if (p == 1 && c < 3)
                stageB(cb ^ 1, c + 1);

            // ---- ds_read fragments of tile t ----
            const int q3 = p / 3;
            const int sh = (q3 - 1) * 58 + (p - q3 * 3) - 1;   // dh*58 + dw

            const bf16_t* abase = &As[tpar][0][0];
            #pragma unroll
            for (int m = 0; m < 4; m++) {
                aF[m][0] = *reinterpret_cast<const bf16x8*>(abase + a_off[m][0]);
                aF[m][1] = *reinterpret_cast<const bf16x8*>(abase + a_off[m][1]);
            }
            const bf16_t* bbase = &Bs[cb][0][0];
            #pragma unroll
            for (int j = 0; j < 7; j++) {
                int pix = base_pix[j] + sh;
                const bf16_t* rp = bbase + pix * 64;
                int key = (pix & 7);
                bF[j][0] = *reinterpret_cast<const bf16x8*>(rp + ((kg       ^ key) * 8));
                bF[j][1] = *reinterpret_cast<const bf16x8*>(rp + (((4 + kg) ^ key) * 8));
            }

            // ---- MFMA (compiler inserts lgkmcnt waits before first use) ----
            PRIO(1);
            #pragma unroll
            for (int m = 0; m < 4; m++)
                #pragma unroll
                for (int j = 0; j < 7; j++) {
                    acc[m][j] = __builtin_amdgcn_mfma_f32_16x16x32_bf16(aF[m][0], bF[j][0], acc[m][j], 0, 0, 0);
                    acc[m][j] = __builtin_amdgcn_mfma_f32_16x16x32_bf16(aF[m][1], bF[j][1], acc[m][j], 0, 0, 0);
                }
            PRIO(0);

            // ---- drain own stages, then release buffers ----
            asm volatile("s_waitcnt vmcnt(0)" ::: "memory");
            BAR();
            SCHED0();
        }
    }

    // ---- epilogue: D row(co) = m*16 + 4*(lane>>4)+i, col(pixel) = j*16 + rl ----
    int hw_off[7];
    #pragma unroll
    for (int j = 0; j < 7; j++) {
        int nn = wc * 112 + j * 16 + rl;
        int br = nn / 56, bc = nn - br * 56;
        hw_off[j] = (R0 + br) * 56 + bc;
    }
    const size_t obase = (size_t)nimg * C_OUT * HW;
    #pragma unroll
    for (int m = 0; m < 4; m++) {
        int cob = co0 + wr * 64 + m * 16 + ((lane >> 4) << 2);
        #pragma unroll
        for (int i = 0; i < 4; i++) {
            int co = cob + i;
            float bv = bias[co];
            float* orow = out + obase + (size_t)co * HW;
            #pragma unroll
            for (int j = 0; j < 7; j++)
                orow[hw_off[j]] = acc[m][j][i] + bv;
        }
    }
}

extern "C" void kernel_launch(void* const* d_in, const int* in_sizes, int n_in,
                              void* d_out, int out_size, void* d_ws, size_t ws_size,
                              hipStream_t stream) {
    const float* x    = (const float*)d_in[0];
    const float* w    = (const float*)d_in[1];
    const float* bias = (const float*)d_in[2];
    float* out = (float*)d_out;

    // workspace: xT halo-padded NHWC bf16 (32*58*58*256*2 = 55.1 MB) then Wt (2.4 MB)
    bf16_t* xT = (bf16_t*)d_ws;
    bf16_t* wt = (bf16_t*)((char*)d_ws + (size_t)NB * HP * HP * C_IN * 2);

    k_halo_zero<<<dim3((NB * 228 * 32 + 255) / 256), dim3(256), 0, stream>>>(xT);
    k_x_nhwc<<<dim3(49, 4, NB), dim3(256), 0, stream>>>(x, xT);
    k_dequant<<<dim3((NQBLK + 255) / 256), dim3(256), 0, stream>>>(w, wt);
    k_conv_gemm<<<dim3(NWG), dim3(512), 0, stream>>>(xT, wt, bias, out);
}